// Round 1
// 216.077 us; speedup vs baseline: 1.3981x; 1.3981x over previous
//
#include <hip/hip_runtime.h>
#include <hip/hip_bf16.h>

// BLSTM: B=1024, T=512, V=128, H=128, HH=64, gates=256/dir.
// R17: structural rewrite of the recurrence — MB=4, quad-duplicated A rows.
//   A[m][k] = h[m>>2][k]  =>  every lane's acc[0..3] are 4 identical copies
//   of gates for batch row `quad`; tiles are gates (i,f,g,o) for j=wave*16+m.
//   Consequences, all VALU cuts vs R16:
//     - gate exchange/select GONE (was 4 DPP + 16 cndmask)
//     - x-term: tab retiled [d][v][j][4] -> ONE dwordx4 gather + 4 v_adds
//       post-MFMA (MFMA C-in = loop-invariant zero; no acc staging movs)
//     - h stored ONCE [4][72] (pad kills bank conflicts); duplication via
//       broadcast addressing (4 lanes/same addr = free); 1 ds_write_b16/lane
//     - 512 blocks of 4 waves -> 2 independent blocks/CU: each SIMD's 2
//       waves are from different barrier groups -> stalls decorrelate.
//   x offsets staged pre-scaled (v<<10) with zero pads both ends so the
//   distance-2 v-prefetch / distance-1 xterm-prefetch never forms a wild
//   global address.

#define T_STEPS 512
#define BATCH   1024
#define VOCAB   128
#define HID     128
#define HH      64
#define NG      256
#define MB      4      // real batch rows per block (quad-duplicated in M)
#define XPAD    8      // xs4 guard rows each end

#define L2E  1.4426950408889634f
#define L2E2 2.8853900817779268f

typedef __attribute__((ext_vector_type(8))) short bf16x8;
typedef __attribute__((ext_vector_type(4))) float f32x4;
typedef unsigned int  u32;
typedef unsigned short u16;

__device__ __forceinline__ float sigmoid_f(float x) {
    return __builtin_amdgcn_rcpf(1.0f + __builtin_amdgcn_exp2f(-x * L2E));
}
__device__ __forceinline__ float tanh_f(float x) {
    return 1.0f - 2.0f * __builtin_amdgcn_rcpf(1.0f + __builtin_amdgcn_exp2f(x * L2E2));
}
__device__ __forceinline__ u16 f2bf_rne(float f) {
    u32 u = __builtin_bit_cast(u32, f);
    u += 0x7FFFu + ((u >> 16) & 1u);
    return (u16)(u >> 16);
}
// barrier with LDS-only drain: global (tab) prefetch loads are NOT drained —
// their vmcnt wait lands at the use point next step.
__device__ __forceinline__ void barrier_lgkm() {
    asm volatile("s_waitcnt lgkmcnt(0)\n\ts_barrier" ::: "memory");
}

// ---------------- Kernel 1: tab build + W_hh bf16 convert (fused) ----------
// tab3 layout: [d][v][j][4] = dot(emb[v], W_ih_d[g*64+j]) for g=i,f,g,o.
__global__ __launch_bounds__(256) void build_tab_kernel(
    const float* __restrict__ emb,
    const float* __restrict__ W_ih_f,
    const float* __restrict__ W_ih_b,
    const float* __restrict__ W_hh_f,
    const float* __restrict__ W_hh_b,
    float* __restrict__ tab3,
    u16*   __restrict__ whh_bf)
{
    int v = blockIdx.x, d = blockIdx.y, tid = threadIdx.x;
    int j = tid >> 2, g = tid & 3;
    int gr = g * HH + j;                      // W_ih gate row
    const float* W = d ? W_ih_b : W_ih_f;
    const float4* e4 = (const float4*)(emb + v * HID);
    const float4* w4 = (const float4*)(W + gr * HID);
    float acc = 0.0f;
#pragma unroll
    for (int k = 0; k < HID / 4; ++k) {
        float4 e = e4[k]; float4 w = w4[k];
        acc += e.x * w.x + e.y * w.y + e.z * w.z + e.w * w.w;
    }
    tab3[(d * VOCAB + v) * NG + j * 4 + g] = acc;

    // fused W_hh convert: plain row-major [2][256][64]
    if (tid < 128) {
        const float* Whh = d ? W_hh_b : W_hh_f;
        int idx = v * 128 + tid;              // 0..16383 within this dir
        whh_bf[d * NG * HH + idx] = f2bf_rne(Whh[idx]);
    }
}

// ---------------- Kernel 2: MFMA recurrence ----------------
// grid (256,2), block 256 (4 waves), 2 blocks/CU.
__global__ __launch_bounds__(256, 2) void lstm_rec_kernel(
    const int*  __restrict__ x,        // [1024][512]
    const u16*  __restrict__ whh_bf,   // [2][256][64] bf16 bits
    const float* __restrict__ tab3,    // [2][128][64][4] floats
    float* __restrict__ hfin)          // [2][1024][64]
{
    __shared__ u32 xs4[T_STEPS + 2 * XPAD][MB];      // v<<10 byte offsets, 8448 B
    __shared__ __align__(16) u16 hbuf[2][MB][72];    // pitch 72 u16 (pad), 1152 B

    const int tid  = threadIdx.x;
    const int lane = tid & 63;
    const int wave = tid >> 6;           // 0..3
    const int quad = lane >> 4;          // 0..3  == my batch row
    const int m    = lane & 15;          // my j within wave's 16
    const int dir    = blockIdx.y;
    const int b_base = blockIdx.x * MB;

    // stage x, pre-scaled to tab3 byte offset (v * 64j * 4g * 4B = v<<10)
    for (int i = tid; i < MB * T_STEPS; i += 256) {
        int bl = i >> 9, t = i & (T_STEPS - 1);
        xs4[XPAD + t][bl] = ((u32)x[(b_base + bl) * T_STEPS + t]) << 10;
    }
    if (tid < MB * XPAD) {               // zero guard rows both ends
        ((u32*)xs4)[tid] = 0;
        ((u32*)xs4)[(XPAD + T_STEPS) * MB + tid] = 0;
    }
    for (int i = tid; i < 2 * MB * 72 / 2; i += 256)   // 288 u32
        ((u32*)hbuf)[i] = 0;

    // persistent B-fragments: tile g = gate g, col m -> gate row g*64+wave*16+m
    const u16* WB = whh_bf + dir * NG * HH;
    bf16x8 Bg[4][2];
#pragma unroll
    for (int g = 0; g < 4; ++g)
#pragma unroll
        for (int kc = 0; kc < 2; ++kc)
            Bg[g][kc] = *(const bf16x8*)(WB + (g * HH + wave * 16 + m) * HH
                                            + kc * 32 + quad * 8);

    const char* tabB = (const char*)(tab3 + dir * VOCAB * NG);
    const u32 joff = (u32)(wave * 16 + m) * 16u;     // j*16 bytes
    const int aoff = (m >> 2) * 72 + quad * 8;       // A-frag read (u16 units)
    const int woff = quad * 72 + wave * 16 + m;      // h write  (u16 units)

    const f32x4 z4 = {0.f, 0.f, 0.f, 0.f};           // loop-invariant C-in
    float cc = 0.f, hcur = 0.f;
    float4 X0, X1;                                    // x-term double buffer
    u32 vA;                                           // v-offset for step s+1

    __syncthreads();   // xs4 + hbuf init visible

    {   // prefetch step 0 x-term + step 1 v-offset
        int ta = XPAD + (dir ? T_STEPS - 1 : 0);
        X0 = *(const float4*)(tabB + xs4[ta][quad] + joff);
        int tb = XPAD + (dir ? T_STEPS - 2 : 1);
        vA = xs4[tb][quad];
    }

    auto stepf = [&](const u16* rh, u16* wh,
                     const float4& Xc, float4& Xn, int s) {
        bf16x8 Ah0 = *(const bf16x8*)(rh + aoff);         // k 0..31
        bf16x8 Ah1 = *(const bf16x8*)(rh + aoff + 32);    // k 32..63

        // issue x-term load for step s+1 (vmcnt wait lands at next use)
        Xn = *(const float4*)(tabB + vA + joff);
        // v-offset prefetch for step s+2 (guard rows make OOB steps safe)
        {
            int t2 = XPAD + (dir ? (T_STEPS - 3 - s) : (s + 2));
            vA = xs4[t2][quad];
        }

        // 4 gate chains, K=64 each; acc[0..3] all equal gates[quad][j]
        f32x4 aI = __builtin_amdgcn_mfma_f32_16x16x32_bf16(Ah0, Bg[0][0], z4, 0, 0, 0);
        f32x4 aF = __builtin_amdgcn_mfma_f32_16x16x32_bf16(Ah0, Bg[1][0], z4, 0, 0, 0);
        f32x4 aG = __builtin_amdgcn_mfma_f32_16x16x32_bf16(Ah0, Bg[2][0], z4, 0, 0, 0);
        f32x4 aO = __builtin_amdgcn_mfma_f32_16x16x32_bf16(Ah0, Bg[3][0], z4, 0, 0, 0);
        aI = __builtin_amdgcn_mfma_f32_16x16x32_bf16(Ah1, Bg[0][1], aI, 0, 0, 0);
        aF = __builtin_amdgcn_mfma_f32_16x16x32_bf16(Ah1, Bg[1][1], aF, 0, 0, 0);
        aG = __builtin_amdgcn_mfma_f32_16x16x32_bf16(Ah1, Bg[2][1], aG, 0, 0, 0);
        aO = __builtin_amdgcn_mfma_f32_16x16x32_bf16(Ah1, Bg[3][1], aO, 0, 0, 0);

        float gi = aI[0] + Xc.x;
        float gf = aF[0] + Xc.y;
        float gg = aG[0] + Xc.z;
        float go = aO[0] + Xc.w;

        cc   = sigmoid_f(gf) * cc + sigmoid_f(gi) * tanh_f(gg);
        hcur = sigmoid_f(go) * tanh_f(cc);

        wh[woff] = f2bf_rne(hcur);       // ONE b16 write; dup via read addr
    };

    for (int it = 0; it < T_STEPS / 2; ++it) {
        stepf(&hbuf[0][0][0], &hbuf[1][0][0], X0, X1, 2 * it);
        barrier_lgkm();
        stepf(&hbuf[1][0][0], &hbuf[0][0][0], X1, X0, 2 * it + 1);
        barrier_lgkm();
    }

    // every thread owns exactly one (b=quad, j)
    hfin[(dir * BATCH + b_base + quad) * HH + wave * 16 + m] = hcur;
}

// ---------------- Kernel 3: final FC (W_fc in LDS, 8 rows/block) ----------
__global__ __launch_bounds__(256) void fc_kernel(
    const float* __restrict__ hfin,    // [2][1024][64]
    const float* __restrict__ W_fc,    // [128][128]
    const float* __restrict__ b_fc,    // [128]
    float* __restrict__ out)           // [1024][128]
{
    __shared__ float wfc[HID * 129];   // row-padded: bank stride 129
    __shared__ float hid[8][HID];
    const int tid = threadIdx.x;
    const int b0  = blockIdx.x * 8;

    for (int i = tid; i < HID * HID; i += 256) {
        int r = i >> 7, c = i & 127;
        wfc[r * 129 + c] = W_fc[i];
    }
    for (int i = tid; i < 8 * HID; i += 256) {
        int bb = i >> 7, v = i & 127;
        hid[bb][v] = (v < HH) ? hfin[(0 * BATCH + b0 + bb) * HH + v]
                              : hfin[(1 * BATCH + b0 + bb) * HH + (v - HH)];
    }
    __syncthreads();

    const int v  = tid & 127;
    const int bs = (tid >> 7) * 4;     // rows [bs, bs+4)
    const float bias = b_fc[v];
    const float* wrow = wfc + v * 129;
#pragma unroll
    for (int r = 0; r < 4; ++r) {
        const float* h = hid[bs + r];
        float acc = bias;
#pragma unroll
        for (int k = 0; k < HID; k += 4) {
            acc += wrow[k]     * h[k]     + wrow[k + 1] * h[k + 1]
                 + wrow[k + 2] * h[k + 2] + wrow[k + 3] * h[k + 3];
        }
        out[(b0 + bs + r) * HID + v] = acc;
    }
}

extern "C" void kernel_launch(void* const* d_in, const int* in_sizes, int n_in,
                              void* d_out, int out_size, void* d_ws, size_t ws_size,
                              hipStream_t stream) {
    const int*   x      = (const int*)d_in[0];
    // d_in[1] = lengths : unused by the reference
    const float* emb    = (const float*)d_in[2];
    const float* W_ih_f = (const float*)d_in[3];
    const float* W_hh_f = (const float*)d_in[4];
    const float* W_ih_b = (const float*)d_in[5];
    const float* W_hh_b = (const float*)d_in[6];
    const float* W_fc   = (const float*)d_in[7];
    const float* b_fc   = (const float*)d_in[8];
    float* out = (float*)d_out;

    float* tab3   = (float*)d_ws;                         // 65536 f32
    u16*   whh_bf = (u16*)(tab3 + 2 * VOCAB * NG);        // 32768 u16
    float* hfin   = (float*)(whh_bf + 2 * NG * HH);       // 131072 f32

    build_tab_kernel<<<dim3(VOCAB, 2), 256, 0, stream>>>(
        emb, W_ih_f, W_ih_b, W_hh_f, W_hh_b, tab3, whh_bf);
    lstm_rec_kernel<<<dim3(BATCH / MB, 2), 256, 0, stream>>>(x, whh_bf, tab3, hfin);
    fc_kernel<<<dim3(BATCH / 8), 256, 0, stream>>>(hfin, W_fc, b_fc, out);
}